// Round 12
// baseline (281.373 us; speedup 1.0000x reference)
//
#include <hip/hip_runtime.h>
#include <math.h>

#define ALPHA 0.2f
#define CAP 64

constexpr int F_IN  = 512;
constexpr int HO    = 256;   // H*O
constexpr int NHEAD = 8;

using bf16x8 = __attribute__((ext_vector_type(8))) short;
using bf16x4 = __attribute__((ext_vector_type(4))) short;
using f32x4  = __attribute__((ext_vector_type(4))) float;

__device__ __forceinline__ ushort f2bf(float f) {
    uint u = __float_as_uint(f);
    uint r = (u + 0x7FFFu + ((u >> 16) & 1u)) >> 16;   // RNE
    return (ushort)r;
}
__device__ __forceinline__ float bf2f(ushort b) {
    return __uint_as_float(((uint)b) << 16);
}

// ---------------- prep: W fragment pack (blocks 0..63) + dst rank/histogram ----------------
__global__ __launch_bounds__(256) void prep_kernel(const float* __restrict__ W,
                                                   ushort* __restrict__ Wf,
                                                   const int* __restrict__ dst,
                                                   int* __restrict__ cnt,
                                                   int* __restrict__ rnk, int E) {
    const int bid = blockIdx.x;
    const int t = threadIdx.x;
    if (bid < 64) {
        int g = bid * 256 + t;                   // 0..16383
        int l   = g & 63;
        int oct = (g >> 6) & 15;
        int ks  = g >> 10;
        int oc  = oct * 16 + (l & 15);
        int hh  = oc >> 5, oo = oc & 31;
        int kb  = ks * 32 + (l >> 4) * 8;
        ushort v[8];
#pragma unroll
        for (int j = 0; j < 8; ++j)
            v[j] = f2bf(W[((size_t)hh * F_IN + kb + j) * 32 + oo]);
        bf16x8 o = { (short)v[0], (short)v[1], (short)v[2], (short)v[3],
                     (short)v[4], (short)v[5], (short)v[6], (short)v[7] };
        *(bf16x8*)(Wf + (size_t)g * 8) = o;
    } else {
        int base = (bid - 64) * 1024;
#pragma unroll
        for (int q = 0; q < 4; ++q) {
            int i = base + q * 256 + t;
            if (i < E) rnk[i] = atomicAdd(&cnt[dst[i]], 1);
        }
    }
}

// ---------------- scan (3-phase) ----------------
__global__ __launch_bounds__(256) void scan1_kernel(const int* __restrict__ cnt,
                                                    int* __restrict__ bsum, int N) {
    __shared__ int red[256];
    const int t = threadIdx.x;
    const int b0 = blockIdx.x * 1024;
    int s = 0;
#pragma unroll
    for (int q = 0; q < 4; ++q) {
        int i = b0 + t * 4 + q;
        if (i < N) s += cnt[i];
    }
    red[t] = s;
    __syncthreads();
    for (int st = 128; st > 0; st >>= 1) {
        if (t < st) red[t] += red[t + st];
        __syncthreads();
    }
    if (t == 0) bsum[blockIdx.x] = red[0];
}

__global__ __launch_bounds__(64) void scan2_kernel(int* __restrict__ bsum, int nblk) {
    int l = threadIdx.x;
    int x = (l < nblk) ? bsum[l] : 0;
    int inc = x;
    for (int d = 1; d < 64; d <<= 1) {
        int v = __shfl_up(inc, d);
        if (l >= d) inc += v;
    }
    if (l < nblk) bsum[l] = inc - x;   // exclusive
}

__global__ __launch_bounds__(256) void scan3_kernel(const int* __restrict__ cnt,
                                                    const int* __restrict__ bsum,
                                                    int* __restrict__ off, int N, int E) {
    __shared__ int part[256];
    const int t = threadIdx.x;
    const int b0 = blockIdx.x * 1024;
    int v[4];
    int s = 0;
#pragma unroll
    for (int q = 0; q < 4; ++q) {
        int i = b0 + t * 4 + q;
        v[q] = (i < N) ? cnt[i] : 0;
        s += v[q];
    }
    part[t] = s;
    __syncthreads();
    for (int d = 1; d < 256; d <<= 1) {
        int x = (t >= d) ? part[t - d] : 0;
        __syncthreads();
        part[t] += x;
        __syncthreads();
    }
    int run = bsum[blockIdx.x] + ((t == 0) ? 0 : part[t - 1]);
#pragma unroll
    for (int q = 0; q < 4; ++q) {
        int i = b0 + t * 4 + q;
        if (i < N) { off[i] = run; run += v[q]; }
    }
    if (blockIdx.x == 0 && t == 0) off[N] = E;
}

// ---------------- place: se[off[dst]+rnk] = src  (no atomics) ----------------
__global__ __launch_bounds__(256) void place_kernel(const int* __restrict__ src,
                                                    const int* __restrict__ dst,
                                                    const int* __restrict__ rnk,
                                                    const int* __restrict__ off,
                                                    int* __restrict__ se, int E) {
    int base = blockIdx.x * 1024;
#pragma unroll
    for (int q = 0; q < 4; ++q) {
        int i = base + q * 256 + threadIdx.x;
        if (i < E) se[off[dst[i]] + rnk[i]] = src[i];
    }
}

// ---------------- MFMA GEMM: tile 128 nodes x 256 outs; 4 waves ----------------
// __launch_bounds__(256,4): 112 VGPR fits 128-cap -> 4 blocks/CU (was 2)
__global__ __launch_bounds__(256, 4) void gemm_kernel(
    const float* __restrict__ h, const ushort* __restrict__ Wf,
    const float* __restrict__ Wb, const float* __restrict__ a,
    ushort* __restrict__ Wh, float* __restrict__ es, float* __restrict__ ed, int N)
{
    __shared__ ushort hs[2][128 * 40];    // 128 rows x 32 k bf16, pitch 40 (80 B)
    const int t = threadIdx.x;
    const int l = t & 63;
    const int w = t >> 6;
    const int l15 = l & 15, l4 = l >> 4;
    const int n0 = blockIdx.x * 128;

    const int sr = t >> 1;                 // staging row 0..127
    const int sc = (t & 1) * 16;           // staging k col 0 or 16
    int srow = n0 + sr; if (srow >= N) srow = N - 1;
    const float* hrow = h + (size_t)srow * F_IN + sc;

    f32x4 acc[4][8];
#pragma unroll
    for (int i = 0; i < 4; ++i)
#pragma unroll
        for (int nt = 0; nt < 8; ++nt) acc[i][nt] = (f32x4){0.f, 0.f, 0.f, 0.f};

    // prologue: stage ks=0 (16 floats -> 16 bf16)
    {
        float4 v0 = *(const float4*)(hrow);
        float4 v1 = *(const float4*)(hrow + 4);
        float4 v2 = *(const float4*)(hrow + 8);
        float4 v3 = *(const float4*)(hrow + 12);
        bf16x8 o0 = { (short)f2bf(v0.x), (short)f2bf(v0.y), (short)f2bf(v0.z), (short)f2bf(v0.w),
                      (short)f2bf(v1.x), (short)f2bf(v1.y), (short)f2bf(v1.z), (short)f2bf(v1.w) };
        bf16x8 o1 = { (short)f2bf(v2.x), (short)f2bf(v2.y), (short)f2bf(v2.z), (short)f2bf(v2.w),
                      (short)f2bf(v3.x), (short)f2bf(v3.y), (short)f2bf(v3.z), (short)f2bf(v3.w) };
        *(bf16x8*)&hs[0][sr * 40 + sc]     = o0;
        *(bf16x8*)&hs[0][sr * 40 + sc + 8] = o1;
    }
    __syncthreads();

    for (int ks = 0; ks < 16; ++ks) {
        const int cb = ks & 1;
        float4 nx0, nx1, nx2, nx3;
        if (ks < 15) {
            const float* p = hrow + (ks + 1) * 32;
            nx0 = *(const float4*)(p);
            nx1 = *(const float4*)(p + 4);
            nx2 = *(const float4*)(p + 8);
            nx3 = *(const float4*)(p + 12);
        }
        bf16x8 af[4];
#pragma unroll
        for (int i = 0; i < 4; ++i)
            af[i] = *(const bf16x8*)(Wf + ((size_t)((ks * 16 + 4 * w + i) * 64 + l)) * 8);
#pragma unroll
        for (int half = 0; half < 2; ++half) {
            bf16x8 b4[4];
#pragma unroll
            for (int j = 0; j < 4; ++j)
                b4[j] = *(const bf16x8*)&hs[cb][((half * 4 + j) * 16 + l15) * 40 + l4 * 8];
#pragma unroll
            for (int i = 0; i < 4; ++i)
#pragma unroll
                for (int j = 0; j < 4; ++j)
                    acc[i][half * 4 + j] = __builtin_amdgcn_mfma_f32_16x16x32_bf16(
                        af[i], b4[j], acc[i][half * 4 + j], 0, 0, 0);
        }
        if (ks < 15) {
            bf16x8 o0 = { (short)f2bf(nx0.x), (short)f2bf(nx0.y), (short)f2bf(nx0.z), (short)f2bf(nx0.w),
                          (short)f2bf(nx1.x), (short)f2bf(nx1.y), (short)f2bf(nx1.z), (short)f2bf(nx1.w) };
            bf16x8 o1 = { (short)f2bf(nx2.x), (short)f2bf(nx2.y), (short)f2bf(nx2.z), (short)f2bf(nx2.w),
                          (short)f2bf(nx3.x), (short)f2bf(nx3.y), (short)f2bf(nx3.z), (short)f2bf(nx3.w) };
            *(bf16x8*)&hs[cb ^ 1][sr * 40 + sc]     = o0;
            *(bf16x8*)&hs[cb ^ 1][sr * 40 + sc + 8] = o1;
            __syncthreads();
        }
    }

    // epilogue (interleaved Wh, node-major es/ed)
    float4 wb4[4], as4[4], ad4[4];
    int ocb[4];
#pragma unroll
    for (int i = 0; i < 4; ++i) {
        int oc_base = (4 * w + i) * 16 + (l4 << 2);
        ocb[i] = oc_base;
        int head = oc_base >> 5;
        wb4[i] = *(const float4*)(Wb + oc_base);
        as4[i] = *(const float4*)(a + head * 64 + (oc_base & 31));
        ad4[i] = *(const float4*)(a + head * 64 + 32 + (oc_base & 31));
    }
#pragma unroll
    for (int nt = 0; nt < 8; ++nt) {
        int node = n0 + nt * 16 + l15;
        bool ok = node < N;
        float pe[4] = {0.f, 0.f, 0.f, 0.f};   // es_h0, es_h1, ed_h0, ed_h1
#pragma unroll
        for (int i = 0; i < 4; ++i) {
            f32x4 v = acc[i][nt];
            float r0 = v.x + wb4[i].x, r1 = v.y + wb4[i].y;
            float r2 = v.z + wb4[i].z, r3 = v.w + wb4[i].w;
            if (ok) {
                bf16x4 o = { (short)f2bf(r0), (short)f2bf(r1), (short)f2bf(r2), (short)f2bf(r3) };
                *(bf16x4*)(Wh + (size_t)node * HO + ocb[i]) = o;
            }
            float dsv = r0 * as4[i].x + r1 * as4[i].y + r2 * as4[i].z + r3 * as4[i].w;
            float ddv = r0 * ad4[i].x + r1 * ad4[i].y + r2 * ad4[i].z + r3 * ad4[i].w;
            int hp = i >> 1;
            pe[hp] += dsv; pe[2 + hp] += ddv;
        }
#pragma unroll
        for (int q = 0; q < 4; ++q) {
            pe[q] += __shfl_xor(pe[q], 16);
            pe[q] += __shfl_xor(pe[q], 32);
        }
        if (l4 == 0 && ok) {
            es[(size_t)node * NHEAD + 2 * w]     = pe[0];
            es[(size_t)node * NHEAD + 2 * w + 1] = pe[1];
            ed[(size_t)node * NHEAD + 2 * w]     = pe[2];
            ed[(size_t)node * NHEAD + 2 * w + 1] = pe[3];
        }
    }
}

// ---------------- per-node softmax + aggregate: 1 wave per node, no max pass ----------------
__global__ __launch_bounds__(256) void node_kernel(
    const int* __restrict__ se, const int* __restrict__ off,
    const float* __restrict__ es, const float* __restrict__ ed,
    const float* __restrict__ ab, const ushort* __restrict__ Wh,
    float* __restrict__ out, int N)
{
    __shared__ float wbuf[4][CAP][NHEAD];
    __shared__ int   sbuf[4][CAP];
    __shared__ float dinv[4][NHEAD];

    const int t = threadIdx.x;
    const int l = t & 63;
    const int wv = t >> 6;
    const int n = blockIdx.x * 4 + wv;
    const bool active = n < N;

    int beg = 0, deg = 0;
    if (active) { beg = off[n]; deg = off[n + 1] - beg; }

    const int slot = l >> 3, hh = l & 7;
    float edn = 0.f, abh = 0.f;
    if (active && deg > 0) {
        edn = ed[(size_t)n * NHEAD + hh];
        abh = ab[hh];
    }

    // pass A: w = exp(leaky(e)), denom; cache w and src in LDS
    float dloc = 0.f;
    for (int j = slot; j < deg; j += 8) {
        int s = se[beg + j];
        float ev = es[(size_t)s * NHEAD + hh] + edn + abh;
        ev = ev > 0.f ? ev : ALPHA * ev;
        float wj = __expf(ev);
        if (j < CAP) {
            wbuf[wv][j][hh] = wj;
            if (hh == 0) sbuf[wv][j] = s;
        }
        dloc += wj;
    }
    dloc += __shfl_xor(dloc, 8);
    dloc += __shfl_xor(dloc, 16);
    dloc += __shfl_xor(dloc, 32);
    if (slot == 0) dinv[wv][hh] = (dloc > 0.f) ? 1.f / dloc : 1.f;
    __syncthreads();

    // pass B: out[n] = (sum_j w_j * Wh[src_j]) * inv   -- 4-deep edge batching
    const int oc0 = (l & 31) * 8;
    const int hb  = oc0 >> 5;
    const int par = l >> 5;
    float acc[8] = {0.f, 0.f, 0.f, 0.f, 0.f, 0.f, 0.f, 0.f};

    if (active) {
        const int dcap = deg < CAP ? deg : CAP;
        int j = par;
        for (; j + 6 < dcap; j += 8) {
            int s0 = sbuf[wv][j];
            int s1 = sbuf[wv][j + 2];
            int s2 = sbuf[wv][j + 4];
            int s3 = sbuf[wv][j + 6];
            float w0 = wbuf[wv][j][hb];
            float w1 = wbuf[wv][j + 2][hb];
            float w2 = wbuf[wv][j + 4][hb];
            float w3 = wbuf[wv][j + 6][hb];
            bf16x8 r0 = *(const bf16x8*)(Wh + (size_t)s0 * HO + oc0);
            bf16x8 r1 = *(const bf16x8*)(Wh + (size_t)s1 * HO + oc0);
            bf16x8 r2 = *(const bf16x8*)(Wh + (size_t)s2 * HO + oc0);
            bf16x8 r3 = *(const bf16x8*)(Wh + (size_t)s3 * HO + oc0);
#pragma unroll
            for (int i = 0; i < 8; ++i) acc[i] += w0 * bf2f((ushort)r0[i]);
#pragma unroll
            for (int i = 0; i < 8; ++i) acc[i] += w1 * bf2f((ushort)r1[i]);
#pragma unroll
            for (int i = 0; i < 8; ++i) acc[i] += w2 * bf2f((ushort)r2[i]);
#pragma unroll
            for (int i = 0; i < 8; ++i) acc[i] += w3 * bf2f((ushort)r3[i]);
        }
        for (; j < dcap; j += 2) {
            int s = sbuf[wv][j];
            float wj = wbuf[wv][j][hb];
            bf16x8 row = *(const bf16x8*)(Wh + (size_t)s * HO + oc0);
#pragma unroll
            for (int i = 0; i < 8; ++i)
                acc[i] += wj * bf2f((ushort)row[i]);
        }
        if (deg > CAP) {   // cold path (deg ~ Poisson(16))
            float edb = ed[(size_t)n * NHEAD + hb] + ab[hb];
            for (int j2 = CAP + par; j2 < deg; j2 += 2) {
                int s = se[beg + j2];
                float ev = es[(size_t)s * NHEAD + hb] + edb;
                ev = ev > 0.f ? ev : ALPHA * ev;
                float wj = __expf(ev);
                bf16x8 row = *(const bf16x8*)(Wh + (size_t)s * HO + oc0);
#pragma unroll
                for (int i = 0; i < 8; ++i)
                    acc[i] += wj * bf2f((ushort)row[i]);
            }
        }
    }
#pragma unroll
    for (int i = 0; i < 8; ++i) acc[i] += __shfl_xor(acc[i], 32);

    if (active && par == 0) {
        float inv = dinv[wv][hb];
        float4 o0 = make_float4(acc[0] * inv, acc[1] * inv, acc[2] * inv, acc[3] * inv);
        float4 o1 = make_float4(acc[4] * inv, acc[5] * inv, acc[6] * inv, acc[7] * inv);
        *(float4*)(out + (size_t)n * HO + oc0)     = o0;
        *(float4*)(out + (size_t)n * HO + oc0 + 4) = o1;
    }
}

// ---------------- launch ----------------
extern "C" void kernel_launch(void* const* d_in, const int* in_sizes, int n_in,
                              void* d_out, int out_size, void* d_ws, size_t ws_size,
                              hipStream_t stream) {
    const float* h   = (const float*)d_in[0];
    const int*   src = (const int*)  d_in[1];
    const int*   dst = (const int*)  d_in[2];
    const float* W   = (const float*)d_in[3];
    const float* Wb  = (const float*)d_in[4];
    const float* a   = (const float*)d_in[5];
    const float* ab  = (const float*)d_in[6];
    float* out = (float*)d_out;

    const int N = in_sizes[0] / F_IN;
    const int E = in_sizes[1];

    auto align_up = [](size_t x) { return (x + 255) & ~size_t(255); };
    char* p = (char*)d_ws;
    ushort* Wh = (ushort*)p; p += align_up((size_t)N * HO * 2);
    float*  es = (float*)p;  p += align_up((size_t)N * NHEAD * 4);
    float*  ed = (float*)p;  p += align_up((size_t)N * NHEAD * 4);
    int* cnt   = (int*)p;    p += align_up((size_t)N * 4);
    int* off   = (int*)p;    p += align_up((size_t)(N + 1) * 4);
    int* rnk   = (int*)p;    p += align_up((size_t)E * 4);
    int* se    = (int*)p;    p += align_up((size_t)E * 4);
    int* bsum  = (int*)p;    p += align_up((size_t)64 * 4);
    ushort* Wf = (ushort*)p; p += align_up((size_t)16 * 16 * 64 * 8 * 2);

    const int nblk = (N + 1023) / 1024;      // 49 for N=50000 (<= 64)
    const int EB   = (E + 1023) / 1024;      // 782 edge blocks
    const int GB   = (N + 127) / 128;        // 391 gemm blocks

    hipMemsetAsync(cnt, 0, (size_t)N * sizeof(int), stream);
    prep_kernel<<<64 + EB, 256, 0, stream>>>(W, Wf, dst, cnt, rnk, E);
    scan1_kernel<<<nblk, 256, 0, stream>>>(cnt, bsum, N);
    scan2_kernel<<<1, 64, 0, stream>>>(bsum, nblk);
    scan3_kernel<<<nblk, 256, 0, stream>>>(cnt, bsum, off, N, E);
    place_kernel<<<EB, 256, 0, stream>>>(src, dst, rnk, off, se, E);
    gemm_kernel<<<GB, 256, 0, stream>>>(h, Wf, Wb, a, Wh, es, ed, N);
    node_kernel<<<(N + 3) / 4, 256, 0, stream>>>(se, off, es, ed, ab, Wh, out, N);
}

// Round 13
// 185.083 us; speedup vs baseline: 1.5203x; 1.5203x over previous
//
#include <hip/hip_runtime.h>
#include <math.h>

#define ALPHA 0.2f
#define CAP 64

constexpr int F_IN  = 512;
constexpr int HO    = 256;   // H*O
constexpr int NHEAD = 8;

using bf16x8 = __attribute__((ext_vector_type(8))) short;
using bf16x4 = __attribute__((ext_vector_type(4))) short;
using f32x4  = __attribute__((ext_vector_type(4))) float;

__device__ __forceinline__ ushort f2bf(float f) {
    uint u = __float_as_uint(f);
    uint r = (u + 0x7FFFu + ((u >> 16) & 1u)) >> 16;   // RNE
    return (ushort)r;
}
__device__ __forceinline__ float bf2f(ushort b) {
    return __uint_as_float(((uint)b) << 16);
}

// ---------------- prep: W fragment pack (blocks 0..63) + dst rank/histogram ----------------
__global__ __launch_bounds__(256) void prep_kernel(const float* __restrict__ W,
                                                   ushort* __restrict__ Wf,
                                                   const int* __restrict__ dst,
                                                   int* __restrict__ cnt,
                                                   int* __restrict__ rnk, int E) {
    const int bid = blockIdx.x;
    const int t = threadIdx.x;
    if (bid < 64) {
        int g = bid * 256 + t;                   // 0..16383
        int l   = g & 63;
        int oct = (g >> 6) & 15;
        int ks  = g >> 10;
        int oc  = oct * 16 + (l & 15);
        int hh  = oc >> 5, oo = oc & 31;
        int kb  = ks * 32 + (l >> 4) * 8;
        ushort v[8];
#pragma unroll
        for (int j = 0; j < 8; ++j)
            v[j] = f2bf(W[((size_t)hh * F_IN + kb + j) * 32 + oo]);
        bf16x8 o = { (short)v[0], (short)v[1], (short)v[2], (short)v[3],
                     (short)v[4], (short)v[5], (short)v[6], (short)v[7] };
        *(bf16x8*)(Wf + (size_t)g * 8) = o;
    } else {
        int base = (bid - 64) * 1024;
#pragma unroll
        for (int q = 0; q < 4; ++q) {
            int i = base + q * 256 + t;
            if (i < E) rnk[i] = atomicAdd(&cnt[dst[i]], 1);
        }
    }
}

// ---------------- scan1: per-block (1024 counts) raw sums ----------------
__global__ __launch_bounds__(256) void scan1_kernel(const int* __restrict__ cnt,
                                                    int* __restrict__ bsum, int N) {
    __shared__ int red[256];
    const int t = threadIdx.x;
    const int b0 = blockIdx.x * 1024;
    int s = 0;
#pragma unroll
    for (int q = 0; q < 4; ++q) {
        int i = b0 + t * 4 + q;
        if (i < N) s += cnt[i];
    }
    red[t] = s;
    __syncthreads();
    for (int st = 128; st > 0; st >>= 1) {
        if (t < st) red[t] += red[t + st];
        __syncthreads();
    }
    if (t == 0) bsum[blockIdx.x] = red[0];
}

// ---------------- scan3: block computes its own prefix from raw bsum ----------------
__global__ __launch_bounds__(256) void scan3_kernel(const int* __restrict__ cnt,
                                                    const int* __restrict__ bsum,
                                                    int* __restrict__ off,
                                                    int N, int E, int nblk) {
    __shared__ int part[256];
    __shared__ int base_s;
    const int t = threadIdx.x;
    const int b0 = blockIdx.x * 1024;

    // wave 0: inclusive shfl-scan of bsum, pick prefix for this block
    if (t < 64) {
        int x = (t < nblk) ? bsum[t] : 0;
        int inc = x;
        for (int d = 1; d < 64; d <<= 1) {
            int v = __shfl_up(inc, d);
            if (t >= d) inc += v;
        }
        int pre = (blockIdx.x == 0) ? 0 : __shfl(inc, (int)blockIdx.x - 1);
        if (t == 0) base_s = pre;
    }

    int v[4];
    int s = 0;
#pragma unroll
    for (int q = 0; q < 4; ++q) {
        int i = b0 + t * 4 + q;
        v[q] = (i < N) ? cnt[i] : 0;
        s += v[q];
    }
    part[t] = s;
    __syncthreads();
    for (int d = 1; d < 256; d <<= 1) {
        int x = (t >= d) ? part[t - d] : 0;
        __syncthreads();
        part[t] += x;
        __syncthreads();
    }
    int run = base_s + ((t == 0) ? 0 : part[t - 1]);
#pragma unroll
    for (int q = 0; q < 4; ++q) {
        int i = b0 + t * 4 + q;
        if (i < N) { off[i] = run; run += v[q]; }
    }
    if (blockIdx.x == 0 && t == 0) off[N] = E;
}

// ---------------- place: se[off[dst]+rnk] = src  (no atomics) ----------------
__global__ __launch_bounds__(256) void place_kernel(const int* __restrict__ src,
                                                    const int* __restrict__ dst,
                                                    const int* __restrict__ rnk,
                                                    const int* __restrict__ off,
                                                    int* __restrict__ se, int E) {
    int base = blockIdx.x * 1024;
#pragma unroll
    for (int q = 0; q < 4; ++q) {
        int i = base + q * 256 + threadIdx.x;
        if (i < E) se[off[dst[i]] + rnk[i]] = src[i];
    }
}

// ---------------- MFMA GEMM: tile 128 nodes x 256 outs; 4 waves ----------------
// (256,3): VGPR cap 170 -> compiler keeps the 112-reg tile (NO spill; (256,4)
// forced 64 VGPR + 260 MB scratch spill, r12), occupancy 8 -> 12 waves/CU.
__global__ __launch_bounds__(256, 3) void gemm_kernel(
    const float* __restrict__ h, const ushort* __restrict__ Wf,
    const float* __restrict__ Wb, const float* __restrict__ a,
    ushort* __restrict__ Wh, float* __restrict__ es, float* __restrict__ ed, int N)
{
    __shared__ ushort hs[2][128 * 40];    // 128 rows x 32 k bf16, pitch 40 (80 B)
    const int t = threadIdx.x;
    const int l = t & 63;
    const int w = t >> 6;
    const int l15 = l & 15, l4 = l >> 4;
    const int n0 = blockIdx.x * 128;

    const int sr = t >> 1;                 // staging row 0..127
    const int sc = (t & 1) * 16;           // staging k col 0 or 16
    int srow = n0 + sr; if (srow >= N) srow = N - 1;
    const float* hrow = h + (size_t)srow * F_IN + sc;

    f32x4 acc[4][8];
#pragma unroll
    for (int i = 0; i < 4; ++i)
#pragma unroll
        for (int nt = 0; nt < 8; ++nt) acc[i][nt] = (f32x4){0.f, 0.f, 0.f, 0.f};

    // prologue: stage ks=0 (16 floats -> 16 bf16)
    {
        float4 v0 = *(const float4*)(hrow);
        float4 v1 = *(const float4*)(hrow + 4);
        float4 v2 = *(const float4*)(hrow + 8);
        float4 v3 = *(const float4*)(hrow + 12);
        bf16x8 o0 = { (short)f2bf(v0.x), (short)f2bf(v0.y), (short)f2bf(v0.z), (short)f2bf(v0.w),
                      (short)f2bf(v1.x), (short)f2bf(v1.y), (short)f2bf(v1.z), (short)f2bf(v1.w) };
        bf16x8 o1 = { (short)f2bf(v2.x), (short)f2bf(v2.y), (short)f2bf(v2.z), (short)f2bf(v2.w),
                      (short)f2bf(v3.x), (short)f2bf(v3.y), (short)f2bf(v3.z), (short)f2bf(v3.w) };
        *(bf16x8*)&hs[0][sr * 40 + sc]     = o0;
        *(bf16x8*)&hs[0][sr * 40 + sc + 8] = o1;
    }
    __syncthreads();

    for (int ks = 0; ks < 16; ++ks) {
        const int cb = ks & 1;
        float4 nx0, nx1, nx2, nx3;
        if (ks < 15) {
            const float* p = hrow + (ks + 1) * 32;
            nx0 = *(const float4*)(p);
            nx1 = *(const float4*)(p + 4);
            nx2 = *(const float4*)(p + 8);
            nx3 = *(const float4*)(p + 12);
        }
        bf16x8 af[4];
#pragma unroll
        for (int i = 0; i < 4; ++i)
            af[i] = *(const bf16x8*)(Wf + ((size_t)((ks * 16 + 4 * w + i) * 64 + l)) * 8);
#pragma unroll
        for (int half = 0; half < 2; ++half) {
            bf16x8 b4[4];
#pragma unroll
            for (int j = 0; j < 4; ++j)
                b4[j] = *(const bf16x8*)&hs[cb][((half * 4 + j) * 16 + l15) * 40 + l4 * 8];
#pragma unroll
            for (int i = 0; i < 4; ++i)
#pragma unroll
                for (int j = 0; j < 4; ++j)
                    acc[i][half * 4 + j] = __builtin_amdgcn_mfma_f32_16x16x32_bf16(
                        af[i], b4[j], acc[i][half * 4 + j], 0, 0, 0);
        }
        if (ks < 15) {
            bf16x8 o0 = { (short)f2bf(nx0.x), (short)f2bf(nx0.y), (short)f2bf(nx0.z), (short)f2bf(nx0.w),
                          (short)f2bf(nx1.x), (short)f2bf(nx1.y), (short)f2bf(nx1.z), (short)f2bf(nx1.w) };
            bf16x8 o1 = { (short)f2bf(nx2.x), (short)f2bf(nx2.y), (short)f2bf(nx2.z), (short)f2bf(nx2.w),
                          (short)f2bf(nx3.x), (short)f2bf(nx3.y), (short)f2bf(nx3.z), (short)f2bf(nx3.w) };
            *(bf16x8*)&hs[cb ^ 1][sr * 40 + sc]     = o0;
            *(bf16x8*)&hs[cb ^ 1][sr * 40 + sc + 8] = o1;
            __syncthreads();
        }
    }

    // epilogue (interleaved Wh, node-major es/ed)
    float4 wb4[4], as4[4], ad4[4];
    int ocb[4];
#pragma unroll
    for (int i = 0; i < 4; ++i) {
        int oc_base = (4 * w + i) * 16 + (l4 << 2);
        ocb[i] = oc_base;
        int head = oc_base >> 5;
        wb4[i] = *(const float4*)(Wb + oc_base);
        as4[i] = *(const float4*)(a + head * 64 + (oc_base & 31));
        ad4[i] = *(const float4*)(a + head * 64 + 32 + (oc_base & 31));
    }
#pragma unroll
    for (int nt = 0; nt < 8; ++nt) {
        int node = n0 + nt * 16 + l15;
        bool ok = node < N;
        float pe[4] = {0.f, 0.f, 0.f, 0.f};   // es_h0, es_h1, ed_h0, ed_h1
#pragma unroll
        for (int i = 0; i < 4; ++i) {
            f32x4 v = acc[i][nt];
            float r0 = v.x + wb4[i].x, r1 = v.y + wb4[i].y;
            float r2 = v.z + wb4[i].z, r3 = v.w + wb4[i].w;
            if (ok) {
                bf16x4 o = { (short)f2bf(r0), (short)f2bf(r1), (short)f2bf(r2), (short)f2bf(r3) };
                *(bf16x4*)(Wh + (size_t)node * HO + ocb[i]) = o;
            }
            float dsv = r0 * as4[i].x + r1 * as4[i].y + r2 * as4[i].z + r3 * as4[i].w;
            float ddv = r0 * ad4[i].x + r1 * ad4[i].y + r2 * ad4[i].z + r3 * ad4[i].w;
            int hp = i >> 1;
            pe[hp] += dsv; pe[2 + hp] += ddv;
        }
#pragma unroll
        for (int q = 0; q < 4; ++q) {
            pe[q] += __shfl_xor(pe[q], 16);
            pe[q] += __shfl_xor(pe[q], 32);
        }
        if (l4 == 0 && ok) {
            es[(size_t)node * NHEAD + 2 * w]     = pe[0];
            es[(size_t)node * NHEAD + 2 * w + 1] = pe[1];
            ed[(size_t)node * NHEAD + 2 * w]     = pe[2];
            ed[(size_t)node * NHEAD + 2 * w + 1] = pe[3];
        }
    }
}

// ---------------- per-node softmax + aggregate: 1 wave per node, no max pass ----------------
__global__ __launch_bounds__(256) void node_kernel(
    const int* __restrict__ se, const int* __restrict__ off,
    const float* __restrict__ es, const float* __restrict__ ed,
    const float* __restrict__ ab, const ushort* __restrict__ Wh,
    float* __restrict__ out, int N)
{
    __shared__ float wbuf[4][CAP][NHEAD];
    __shared__ int   sbuf[4][CAP];
    __shared__ float dinv[4][NHEAD];

    const int t = threadIdx.x;
    const int l = t & 63;
    const int wv = t >> 6;
    const int n = blockIdx.x * 4 + wv;
    const bool active = n < N;

    int beg = 0, deg = 0;
    if (active) { beg = off[n]; deg = off[n + 1] - beg; }

    const int slot = l >> 3, hh = l & 7;
    float edn = 0.f, abh = 0.f;
    if (active && deg > 0) {
        edn = ed[(size_t)n * NHEAD + hh];
        abh = ab[hh];
    }

    // pass A: w = exp(leaky(e)), denom; cache w and src in LDS
    float dloc = 0.f;
    for (int j = slot; j < deg; j += 8) {
        int s = se[beg + j];
        float ev = es[(size_t)s * NHEAD + hh] + edn + abh;
        ev = ev > 0.f ? ev : ALPHA * ev;
        float wj = __expf(ev);
        if (j < CAP) {
            wbuf[wv][j][hh] = wj;
            if (hh == 0) sbuf[wv][j] = s;
        }
        dloc += wj;
    }
    dloc += __shfl_xor(dloc, 8);
    dloc += __shfl_xor(dloc, 16);
    dloc += __shfl_xor(dloc, 32);
    if (slot == 0) dinv[wv][hh] = (dloc > 0.f) ? 1.f / dloc : 1.f;
    __syncthreads();

    // pass B: out[n] = (sum_j w_j * Wh[src_j]) * inv   -- 4-deep edge batching
    const int oc0 = (l & 31) * 8;
    const int hb  = oc0 >> 5;
    const int par = l >> 5;
    float acc[8] = {0.f, 0.f, 0.f, 0.f, 0.f, 0.f, 0.f, 0.f};

    if (active) {
        const int dcap = deg < CAP ? deg : CAP;
        int j = par;
        for (; j + 6 < dcap; j += 8) {
            int s0 = sbuf[wv][j];
            int s1 = sbuf[wv][j + 2];
            int s2 = sbuf[wv][j + 4];
            int s3 = sbuf[wv][j + 6];
            float w0 = wbuf[wv][j][hb];
            float w1 = wbuf[wv][j + 2][hb];
            float w2 = wbuf[wv][j + 4][hb];
            float w3 = wbuf[wv][j + 6][hb];
            bf16x8 r0 = *(const bf16x8*)(Wh + (size_t)s0 * HO + oc0);
            bf16x8 r1 = *(const bf16x8*)(Wh + (size_t)s1 * HO + oc0);
            bf16x8 r2 = *(const bf16x8*)(Wh + (size_t)s2 * HO + oc0);
            bf16x8 r3 = *(const bf16x8*)(Wh + (size_t)s3 * HO + oc0);
#pragma unroll
            for (int i = 0; i < 8; ++i) acc[i] += w0 * bf2f((ushort)r0[i]);
#pragma unroll
            for (int i = 0; i < 8; ++i) acc[i] += w1 * bf2f((ushort)r1[i]);
#pragma unroll
            for (int i = 0; i < 8; ++i) acc[i] += w2 * bf2f((ushort)r2[i]);
#pragma unroll
            for (int i = 0; i < 8; ++i) acc[i] += w3 * bf2f((ushort)r3[i]);
        }
        for (; j < dcap; j += 2) {
            int s = sbuf[wv][j];
            float wj = wbuf[wv][j][hb];
            bf16x8 row = *(const bf16x8*)(Wh + (size_t)s * HO + oc0);
#pragma unroll
            for (int i = 0; i < 8; ++i)
                acc[i] += wj * bf2f((ushort)row[i]);
        }
        if (deg > CAP) {   // cold path (deg ~ Poisson(16))
            float edb = ed[(size_t)n * NHEAD + hb] + ab[hb];
            for (int j2 = CAP + par; j2 < deg; j2 += 2) {
                int s = se[beg + j2];
                float ev = es[(size_t)s * NHEAD + hb] + edb;
                ev = ev > 0.f ? ev : ALPHA * ev;
                float wj = __expf(ev);
                bf16x8 row = *(const bf16x8*)(Wh + (size_t)s * HO + oc0);
#pragma unroll
                for (int i = 0; i < 8; ++i)
                    acc[i] += wj * bf2f((ushort)row[i]);
            }
        }
    }
#pragma unroll
    for (int i = 0; i < 8; ++i) acc[i] += __shfl_xor(acc[i], 32);

    if (active && par == 0) {
        float inv = dinv[wv][hb];
        float4 o0 = make_float4(acc[0] * inv, acc[1] * inv, acc[2] * inv, acc[3] * inv);
        float4 o1 = make_float4(acc[4] * inv, acc[5] * inv, acc[6] * inv, acc[7] * inv);
        *(float4*)(out + (size_t)n * HO + oc0)     = o0;
        *(float4*)(out + (size_t)n * HO + oc0 + 4) = o1;
    }
}

// ---------------- launch ----------------
extern "C" void kernel_launch(void* const* d_in, const int* in_sizes, int n_in,
                              void* d_out, int out_size, void* d_ws, size_t ws_size,
                              hipStream_t stream) {
    const float* h   = (const float*)d_in[0];
    const int*   src = (const int*)  d_in[1];
    const int*   dst = (const int*)  d_in[2];
    const float* W   = (const float*)d_in[3];
    const float* Wb  = (const float*)d_in[4];
    const float* a   = (const float*)d_in[5];
    const float* ab  = (const float*)d_in[6];
    float* out = (float*)d_out;

    const int N = in_sizes[0] / F_IN;
    const int E = in_sizes[1];

    auto align_up = [](size_t x) { return (x + 255) & ~size_t(255); };
    char* p = (char*)d_ws;
    ushort* Wh = (ushort*)p; p += align_up((size_t)N * HO * 2);
    float*  es = (float*)p;  p += align_up((size_t)N * NHEAD * 4);
    float*  ed = (float*)p;  p += align_up((size_t)N * NHEAD * 4);
    int* cnt   = (int*)p;    p += align_up((size_t)N * 4);
    int* off   = (int*)p;    p += align_up((size_t)(N + 1) * 4);
    int* rnk   = (int*)p;    p += align_up((size_t)E * 4);
    int* se    = (int*)p;    p += align_up((size_t)E * 4);
    int* bsum  = (int*)p;    p += align_up((size_t)64 * 4);
    ushort* Wf = (ushort*)p; p += align_up((size_t)16 * 16 * 64 * 8 * 2);

    const int nblk = (N + 1023) / 1024;      // 49 for N=50000 (<= 64)
    const int EB   = (E + 1023) / 1024;      // 782 edge blocks
    const int GB   = (N + 127) / 128;        // 391 gemm blocks

    hipMemsetAsync(cnt, 0, (size_t)N * sizeof(int), stream);
    prep_kernel<<<64 + EB, 256, 0, stream>>>(W, Wf, dst, cnt, rnk, E);
    scan1_kernel<<<nblk, 256, 0, stream>>>(cnt, bsum, N);
    scan3_kernel<<<nblk, 256, 0, stream>>>(cnt, bsum, off, N, E, nblk);
    place_kernel<<<EB, 256, 0, stream>>>(src, dst, rnk, off, se, E);
    gemm_kernel<<<GB, 256, 0, stream>>>(h, Wf, Wb, a, Wh, es, ed, N);
    node_kernel<<<(N + 3) / 4, 256, 0, stream>>>(se, off, es, ed, ab, Wh, out, N);
}

// Round 14
// 162.881 us; speedup vs baseline: 1.7275x; 1.1363x over previous
//
#include <hip/hip_runtime.h>
#include <math.h>

#define ALPHA 0.2f
#define CAP 64

constexpr int F_IN  = 512;
constexpr int HO    = 256;   // H*O
constexpr int NHEAD = 8;

using bf16x8 = __attribute__((ext_vector_type(8))) short;
using bf16x4 = __attribute__((ext_vector_type(4))) short;
using f32x4  = __attribute__((ext_vector_type(4))) float;

__device__ __forceinline__ ushort f2bf(float f) {
    uint u = __float_as_uint(f);
    uint r = (u + 0x7FFFu + ((u >> 16) & 1u)) >> 16;   // RNE
    return (ushort)r;
}
__device__ __forceinline__ float bf2f(ushort b) {
    return __uint_as_float(((uint)b) << 16);
}

// ---------------- prep: W fragment pack (blocks 0..63) + dst rank/histogram ----------------
__global__ __launch_bounds__(256) void prep_kernel(const float* __restrict__ W,
                                                   ushort* __restrict__ Wf,
                                                   const int* __restrict__ dst,
                                                   int* __restrict__ cnt,
                                                   int* __restrict__ rnk, int E) {
    const int bid = blockIdx.x;
    const int t = threadIdx.x;
    if (bid < 64) {
        int g = bid * 256 + t;                   // 0..16383
        int l   = g & 63;
        int oct = (g >> 6) & 15;
        int ks  = g >> 10;
        int oc  = oct * 16 + (l & 15);
        int hh  = oc >> 5, oo = oc & 31;
        int kb  = ks * 32 + (l >> 4) * 8;
        ushort v[8];
#pragma unroll
        for (int j = 0; j < 8; ++j)
            v[j] = f2bf(W[((size_t)hh * F_IN + kb + j) * 32 + oo]);
        bf16x8 o = { (short)v[0], (short)v[1], (short)v[2], (short)v[3],
                     (short)v[4], (short)v[5], (short)v[6], (short)v[7] };
        *(bf16x8*)(Wf + (size_t)g * 8) = o;
    } else {
        int base = (bid - 64) * 1024;
#pragma unroll
        for (int q = 0; q < 4; ++q) {
            int i = base + q * 256 + t;
            if (i < E) rnk[i] = atomicAdd(&cnt[dst[i]], 1);
        }
    }
}

// ---------------- scan1: per-block (1024 counts) raw sums ----------------
__global__ __launch_bounds__(256) void scan1_kernel(const int* __restrict__ cnt,
                                                    int* __restrict__ bsum, int N) {
    __shared__ int red[256];
    const int t = threadIdx.x;
    const int b0 = blockIdx.x * 1024;
    int s = 0;
#pragma unroll
    for (int q = 0; q < 4; ++q) {
        int i = b0 + t * 4 + q;
        if (i < N) s += cnt[i];
    }
    red[t] = s;
    __syncthreads();
    for (int st = 128; st > 0; st >>= 1) {
        if (t < st) red[t] += red[t + st];
        __syncthreads();
    }
    if (t == 0) bsum[blockIdx.x] = red[0];
}

// ---------------- scan3: block computes its own prefix from raw bsum ----------------
__global__ __launch_bounds__(256) void scan3_kernel(const int* __restrict__ cnt,
                                                    const int* __restrict__ bsum,
                                                    int* __restrict__ off,
                                                    int N, int E, int nblk) {
    __shared__ int part[256];
    __shared__ int base_s;
    const int t = threadIdx.x;
    const int b0 = blockIdx.x * 1024;

    // wave 0: inclusive shfl-scan of bsum, pick prefix for this block
    if (t < 64) {
        int x = (t < nblk) ? bsum[t] : 0;
        int inc = x;
        for (int d = 1; d < 64; d <<= 1) {
            int v = __shfl_up(inc, d);
            if (t >= d) inc += v;
        }
        int pre = (blockIdx.x == 0) ? 0 : __shfl(inc, (int)blockIdx.x - 1);
        if (t == 0) base_s = pre;
    }

    int v[4];
    int s = 0;
#pragma unroll
    for (int q = 0; q < 4; ++q) {
        int i = b0 + t * 4 + q;
        v[q] = (i < N) ? cnt[i] : 0;
        s += v[q];
    }
    part[t] = s;
    __syncthreads();
    for (int d = 1; d < 256; d <<= 1) {
        int x = (t >= d) ? part[t - d] : 0;
        __syncthreads();
        part[t] += x;
        __syncthreads();
    }
    int run = base_s + ((t == 0) ? 0 : part[t - 1]);
#pragma unroll
    for (int q = 0; q < 4; ++q) {
        int i = b0 + t * 4 + q;
        if (i < N) { off[i] = run; run += v[q]; }
    }
    if (blockIdx.x == 0 && t == 0) off[N] = E;
}

// ---------------- place: se[off[dst]+rnk] = src  (no atomics) ----------------
__global__ __launch_bounds__(256) void place_kernel(const int* __restrict__ src,
                                                    const int* __restrict__ dst,
                                                    const int* __restrict__ rnk,
                                                    const int* __restrict__ off,
                                                    int* __restrict__ se, int E) {
    int base = blockIdx.x * 1024;
#pragma unroll
    for (int q = 0; q < 4; ++q) {
        int i = base + q * 256 + threadIdx.x;
        if (i < E) se[off[dst[i]] + rnk[i]] = src[i];
    }
}

// ---------------- MFMA GEMM: tile 128 nodes x 256 outs; 4 waves ----------------
// (256,2) ONLY: the acc[4][8] tile needs ~112 VGPR. (256,3) -> 84 VGPR + spill
// (r13: WRITE 54MB, 80us); (256,4) -> 64 VGPR + 260MB spill (r12: 173us).
__global__ __launch_bounds__(256, 2) void gemm_kernel(
    const float* __restrict__ h, const ushort* __restrict__ Wf,
    const float* __restrict__ Wb, const float* __restrict__ a,
    ushort* __restrict__ Wh, float* __restrict__ es, float* __restrict__ ed, int N)
{
    __shared__ ushort hs[2][128 * 40];    // 128 rows x 32 k bf16, pitch 40 (80 B)
    const int t = threadIdx.x;
    const int l = t & 63;
    const int w = t >> 6;
    const int l15 = l & 15, l4 = l >> 4;
    const int n0 = blockIdx.x * 128;

    const int sr = t >> 1;                 // staging row 0..127
    const int sc = (t & 1) * 16;           // staging k col 0 or 16
    int srow = n0 + sr; if (srow >= N) srow = N - 1;
    const float* hrow = h + (size_t)srow * F_IN + sc;

    f32x4 acc[4][8];
#pragma unroll
    for (int i = 0; i < 4; ++i)
#pragma unroll
        for (int nt = 0; nt < 8; ++nt) acc[i][nt] = (f32x4){0.f, 0.f, 0.f, 0.f};

    // prologue: stage ks=0 (16 floats -> 16 bf16)
    {
        float4 v0 = *(const float4*)(hrow);
        float4 v1 = *(const float4*)(hrow + 4);
        float4 v2 = *(const float4*)(hrow + 8);
        float4 v3 = *(const float4*)(hrow + 12);
        bf16x8 o0 = { (short)f2bf(v0.x), (short)f2bf(v0.y), (short)f2bf(v0.z), (short)f2bf(v0.w),
                      (short)f2bf(v1.x), (short)f2bf(v1.y), (short)f2bf(v1.z), (short)f2bf(v1.w) };
        bf16x8 o1 = { (short)f2bf(v2.x), (short)f2bf(v2.y), (short)f2bf(v2.z), (short)f2bf(v2.w),
                      (short)f2bf(v3.x), (short)f2bf(v3.y), (short)f2bf(v3.z), (short)f2bf(v3.w) };
        *(bf16x8*)&hs[0][sr * 40 + sc]     = o0;
        *(bf16x8*)&hs[0][sr * 40 + sc + 8] = o1;
    }
    __syncthreads();

    for (int ks = 0; ks < 16; ++ks) {
        const int cb = ks & 1;
        float4 nx0, nx1, nx2, nx3;
        if (ks < 15) {
            const float* p = hrow + (ks + 1) * 32;
            nx0 = *(const float4*)(p);
            nx1 = *(const float4*)(p + 4);
            nx2 = *(const float4*)(p + 8);
            nx3 = *(const float4*)(p + 12);
        }
        bf16x8 af[4];
#pragma unroll
        for (int i = 0; i < 4; ++i)
            af[i] = *(const bf16x8*)(Wf + ((size_t)((ks * 16 + 4 * w + i) * 64 + l)) * 8);
#pragma unroll
        for (int half = 0; half < 2; ++half) {
            bf16x8 b4[4];
#pragma unroll
            for (int j = 0; j < 4; ++j)
                b4[j] = *(const bf16x8*)&hs[cb][((half * 4 + j) * 16 + l15) * 40 + l4 * 8];
#pragma unroll
            for (int i = 0; i < 4; ++i)
#pragma unroll
                for (int j = 0; j < 4; ++j)
                    acc[i][half * 4 + j] = __builtin_amdgcn_mfma_f32_16x16x32_bf16(
                        af[i], b4[j], acc[i][half * 4 + j], 0, 0, 0);
        }
        if (ks < 15) {
            bf16x8 o0 = { (short)f2bf(nx0.x), (short)f2bf(nx0.y), (short)f2bf(nx0.z), (short)f2bf(nx0.w),
                          (short)f2bf(nx1.x), (short)f2bf(nx1.y), (short)f2bf(nx1.z), (short)f2bf(nx1.w) };
            bf16x8 o1 = { (short)f2bf(nx2.x), (short)f2bf(nx2.y), (short)f2bf(nx2.z), (short)f2bf(nx2.w),
                          (short)f2bf(nx3.x), (short)f2bf(nx3.y), (short)f2bf(nx3.z), (short)f2bf(nx3.w) };
            *(bf16x8*)&hs[cb ^ 1][sr * 40 + sc]     = o0;
            *(bf16x8*)&hs[cb ^ 1][sr * 40 + sc + 8] = o1;
            __syncthreads();
        }
    }

    // epilogue (interleaved Wh, node-major es/ed)
    float4 wb4[4], as4[4], ad4[4];
    int ocb[4];
#pragma unroll
    for (int i = 0; i < 4; ++i) {
        int oc_base = (4 * w + i) * 16 + (l4 << 2);
        ocb[i] = oc_base;
        int head = oc_base >> 5;
        wb4[i] = *(const float4*)(Wb + oc_base);
        as4[i] = *(const float4*)(a + head * 64 + (oc_base & 31));
        ad4[i] = *(const float4*)(a + head * 64 + 32 + (oc_base & 31));
    }
#pragma unroll
    for (int nt = 0; nt < 8; ++nt) {
        int node = n0 + nt * 16 + l15;
        bool ok = node < N;
        float pe[4] = {0.f, 0.f, 0.f, 0.f};   // es_h0, es_h1, ed_h0, ed_h1
#pragma unroll
        for (int i = 0; i < 4; ++i) {
            f32x4 v = acc[i][nt];
            float r0 = v.x + wb4[i].x, r1 = v.y + wb4[i].y;
            float r2 = v.z + wb4[i].z, r3 = v.w + wb4[i].w;
            if (ok) {
                bf16x4 o = { (short)f2bf(r0), (short)f2bf(r1), (short)f2bf(r2), (short)f2bf(r3) };
                *(bf16x4*)(Wh + (size_t)node * HO + ocb[i]) = o;
            }
            float dsv = r0 * as4[i].x + r1 * as4[i].y + r2 * as4[i].z + r3 * as4[i].w;
            float ddv = r0 * ad4[i].x + r1 * ad4[i].y + r2 * ad4[i].z + r3 * ad4[i].w;
            int hp = i >> 1;
            pe[hp] += dsv; pe[2 + hp] += ddv;
        }
#pragma unroll
        for (int q = 0; q < 4; ++q) {
            pe[q] += __shfl_xor(pe[q], 16);
            pe[q] += __shfl_xor(pe[q], 32);
        }
        if (l4 == 0 && ok) {
            es[(size_t)node * NHEAD + 2 * w]     = pe[0];
            es[(size_t)node * NHEAD + 2 * w + 1] = pe[1];
            ed[(size_t)node * NHEAD + 2 * w]     = pe[2];
            ed[(size_t)node * NHEAD + 2 * w + 1] = pe[3];
        }
    }
}

// ---------------- per-node softmax + aggregate: 1 wave per node, no max pass ----------------
__global__ __launch_bounds__(256) void node_kernel(
    const int* __restrict__ se, const int* __restrict__ off,
    const float* __restrict__ es, const float* __restrict__ ed,
    const float* __restrict__ ab, const ushort* __restrict__ Wh,
    float* __restrict__ out, int N)
{
    __shared__ float wbuf[4][CAP][NHEAD];
    __shared__ int   sbuf[4][CAP];
    __shared__ float dinv[4][NHEAD];

    const int t = threadIdx.x;
    const int l = t & 63;
    const int wv = t >> 6;
    const int n = blockIdx.x * 4 + wv;
    const bool active = n < N;

    int beg = 0, deg = 0;
    if (active) { beg = off[n]; deg = off[n + 1] - beg; }

    const int slot = l >> 3, hh = l & 7;
    float edn = 0.f, abh = 0.f;
    if (active && deg > 0) {
        edn = ed[(size_t)n * NHEAD + hh];
        abh = ab[hh];
    }

    // pass A: w = exp(leaky(e)), denom; cache w and src in LDS
    float dloc = 0.f;
    for (int j = slot; j < deg; j += 8) {
        int s = se[beg + j];
        float ev = es[(size_t)s * NHEAD + hh] + edn + abh;
        ev = ev > 0.f ? ev : ALPHA * ev;
        float wj = __expf(ev);
        if (j < CAP) {
            wbuf[wv][j][hh] = wj;
            if (hh == 0) sbuf[wv][j] = s;
        }
        dloc += wj;
    }
    dloc += __shfl_xor(dloc, 8);
    dloc += __shfl_xor(dloc, 16);
    dloc += __shfl_xor(dloc, 32);
    if (slot == 0) dinv[wv][hh] = (dloc > 0.f) ? 1.f / dloc : 1.f;
    __syncthreads();

    // pass B: out[n] = (sum_j w_j * Wh[src_j]) * inv   -- 4-deep edge batching
    const int oc0 = (l & 31) * 8;
    const int hb  = oc0 >> 5;
    const int par = l >> 5;
    float acc[8] = {0.f, 0.f, 0.f, 0.f, 0.f, 0.f, 0.f, 0.f};

    if (active) {
        const int dcap = deg < CAP ? deg : CAP;
        int j = par;
        for (; j + 6 < dcap; j += 8) {
            int s0 = sbuf[wv][j];
            int s1 = sbuf[wv][j + 2];
            int s2 = sbuf[wv][j + 4];
            int s3 = sbuf[wv][j + 6];
            float w0 = wbuf[wv][j][hb];
            float w1 = wbuf[wv][j + 2][hb];
            float w2 = wbuf[wv][j + 4][hb];
            float w3 = wbuf[wv][j + 6][hb];
            bf16x8 r0 = *(const bf16x8*)(Wh + (size_t)s0 * HO + oc0);
            bf16x8 r1 = *(const bf16x8*)(Wh + (size_t)s1 * HO + oc0);
            bf16x8 r2 = *(const bf16x8*)(Wh + (size_t)s2 * HO + oc0);
            bf16x8 r3 = *(const bf16x8*)(Wh + (size_t)s3 * HO + oc0);
#pragma unroll
            for (int i = 0; i < 8; ++i) acc[i] += w0 * bf2f((ushort)r0[i]);
#pragma unroll
            for (int i = 0; i < 8; ++i) acc[i] += w1 * bf2f((ushort)r1[i]);
#pragma unroll
            for (int i = 0; i < 8; ++i) acc[i] += w2 * bf2f((ushort)r2[i]);
#pragma unroll
            for (int i = 0; i < 8; ++i) acc[i] += w3 * bf2f((ushort)r3[i]);
        }
        for (; j < dcap; j += 2) {
            int s = sbuf[wv][j];
            float wj = wbuf[wv][j][hb];
            bf16x8 row = *(const bf16x8*)(Wh + (size_t)s * HO + oc0);
#pragma unroll
            for (int i = 0; i < 8; ++i)
                acc[i] += wj * bf2f((ushort)row[i]);
        }
        if (deg > CAP) {   // cold path (deg ~ Poisson(16))
            float edb = ed[(size_t)n * NHEAD + hb] + ab[hb];
            for (int j2 = CAP + par; j2 < deg; j2 += 2) {
                int s = se[beg + j2];
                float ev = es[(size_t)s * NHEAD + hb] + edb;
                ev = ev > 0.f ? ev : ALPHA * ev;
                float wj = __expf(ev);
                bf16x8 row = *(const bf16x8*)(Wh + (size_t)s * HO + oc0);
#pragma unroll
                for (int i = 0; i < 8; ++i)
                    acc[i] += wj * bf2f((ushort)row[i]);
            }
        }
    }
#pragma unroll
    for (int i = 0; i < 8; ++i) acc[i] += __shfl_xor(acc[i], 32);

    if (active && par == 0) {
        float inv = dinv[wv][hb];
        float4 o0 = make_float4(acc[0] * inv, acc[1] * inv, acc[2] * inv, acc[3] * inv);
        float4 o1 = make_float4(acc[4] * inv, acc[5] * inv, acc[6] * inv, acc[7] * inv);
        *(float4*)(out + (size_t)n * HO + oc0)     = o0;
        *(float4*)(out + (size_t)n * HO + oc0 + 4) = o1;
    }
}

// ---------------- launch ----------------
extern "C" void kernel_launch(void* const* d_in, const int* in_sizes, int n_in,
                              void* d_out, int out_size, void* d_ws, size_t ws_size,
                              hipStream_t stream) {
    const float* h   = (const float*)d_in[0];
    const int*   src = (const int*)  d_in[1];
    const int*   dst = (const int*)  d_in[2];
    const float* W   = (const float*)d_in[3];
    const float* Wb  = (const float*)d_in[4];
    const float* a   = (const float*)d_in[5];
    const float* ab  = (const float*)d_in[6];
    float* out = (float*)d_out;

    const int N = in_sizes[0] / F_IN;
    const int E = in_sizes[1];

    auto align_up = [](size_t x) { return (x + 255) & ~size_t(255); };
    char* p = (char*)d_ws;
    ushort* Wh = (ushort*)p; p += align_up((size_t)N * HO * 2);
    float*  es = (float*)p;  p += align_up((size_t)N * NHEAD * 4);
    float*  ed = (float*)p;  p += align_up((size_t)N * NHEAD * 4);
    int* cnt   = (int*)p;    p += align_up((size_t)N * 4);
    int* off   = (int*)p;    p += align_up((size_t)(N + 1) * 4);
    int* rnk   = (int*)p;    p += align_up((size_t)E * 4);
    int* se    = (int*)p;    p += align_up((size_t)E * 4);
    int* bsum  = (int*)p;    p += align_up((size_t)64 * 4);
    ushort* Wf = (ushort*)p; p += align_up((size_t)16 * 16 * 64 * 8 * 2);

    const int nblk = (N + 1023) / 1024;      // 49 for N=50000 (<= 64)
    const int EB   = (E + 1023) / 1024;      // 782 edge blocks
    const int GB   = (N + 127) / 128;        // 391 gemm blocks

    hipMemsetAsync(cnt, 0, (size_t)N * sizeof(int), stream);
    prep_kernel<<<64 + EB, 256, 0, stream>>>(W, Wf, dst, cnt, rnk, E);
    scan1_kernel<<<nblk, 256, 0, stream>>>(cnt, bsum, N);
    scan3_kernel<<<nblk, 256, 0, stream>>>(cnt, bsum, off, N, E, nblk);
    place_kernel<<<EB, 256, 0, stream>>>(src, dst, rnk, off, se, E);
    gemm_kernel<<<GB, 256, 0, stream>>>(h, Wf, Wb, a, Wh, es, ed, N);
    node_kernel<<<(N + 3) / 4, 256, 0, stream>>>(se, off, es, ed, ab, Wh, out, N);
}